// Round 5
// baseline (220.588 us; speedup 1.0000x reference)
//
#include <hip/hip_runtime.h>

#define S_TOKENS 16384
#define DMODEL   2048
#define NE       8
#define CAPACITY 2560

// ws layout (4-byte units):
//   [0, 16384)      int    expert idx per token
//   [16384, 32768)  float  gate per token
//   [32768, 37376)  float  partials[9][512]  (q-major: psum[0..7], zsum at q=8)
//   [37376, 41472)  int    hist[512][8]  per-logits-block expert counts (32 tokens each)

__global__ __launch_bounds__(512) void logits_kernel(
    const float* __restrict__ x, const float* __restrict__ W,
    int* __restrict__ idx_out, float* __restrict__ gate_out,
    float* __restrict__ partials, int* __restrict__ hist) {
    __shared__ float4 Ws4[NE][DMODEL/4];   // 64 KB, expert-major: conflict-free b128
    __shared__ float  sacc[16];            // [0..7] psum, [8] zsum
    __shared__ int    shist[8];

    const int tid  = threadIdx.x;
    const int wave = tid >> 6;
    const int lane = tid & 63;

    if (tid < 16) sacc[tid] = 0.0f;
    if (tid < 8)  shist[tid] = 0;
    {
        const float4* __restrict__ Wg = (const float4*)W;
        float4* Wl = (float4*)Ws4;
        #pragma unroll
        for (int i = 0; i < 8; ++i) Wl[i*512 + tid] = Wg[i*512 + tid];
    }
    __syncthreads();

    // 4 tokens per wave: block covers 32 tokens
    const int token0 = blockIdx.x * 32 + wave * 4;
    const float4* __restrict__ x0 = (const float4*)(x + (size_t)token0 * DMODEL);
    const float4* __restrict__ x1 = x0 + 512;
    const float4* __restrict__ x2 = x0 + 1024;
    const float4* __restrict__ x3 = x0 + 1536;

    float a0[NE], a1[NE], a2[NE], a3[NE];
    #pragma unroll
    for (int e = 0; e < NE; ++e) { a0[e]=0; a1[e]=0; a2[e]=0; a3[e]=0; }

    // bounded unroll: keep load live-set small, no spill
    #pragma unroll 2
    for (int i = 0; i < 8; ++i) {
        const int j4 = i*64 + lane;
        float4 xv0 = x0[j4];
        float4 xv1 = x1[j4];
        float4 xv2 = x2[j4];
        float4 xv3 = x3[j4];
        #pragma unroll
        for (int e = 0; e < NE; ++e) {
            float4 w = Ws4[e][j4];
            a0[e] += xv0.x*w.x + xv0.y*w.y + xv0.z*w.z + xv0.w*w.w;
            a1[e] += xv1.x*w.x + xv1.y*w.y + xv1.z*w.z + xv1.w*w.w;
            a2[e] += xv2.x*w.x + xv2.y*w.y + xv2.z*w.z + xv2.w*w.w;
            a3[e] += xv3.x*w.x + xv3.y*w.y + xv3.z*w.z + xv3.w*w.w;
        }
    }

    // reduction with token-halving: lanes [q*16, q*16+16) end owning token q
    const bool hiHalf = (lane & 32) != 0;
    const bool oddQ   = (lane & 16) != 0;
    float lg[NE];
    #pragma unroll
    for (int e = 0; e < NE; ++e) {
        float s0 = a0[e] + __shfl_xor(a0[e], 32);
        float s1 = a1[e] + __shfl_xor(a1[e], 32);
        float s2 = a2[e] + __shfl_xor(a2[e], 32);
        float s3 = a3[e] + __shfl_xor(a3[e], 32);
        float u = hiHalf ? s2 : s0;
        float v = hiHalf ? s3 : s1;
        u += __shfl_xor(u, 16);
        v += __shfl_xor(v, 16);
        float r = oddQ ? v : u;
        r += __shfl_xor(r, 8);
        r += __shfl_xor(r, 4);
        r += __shfl_xor(r, 2);
        r += __shfl_xor(r, 1);
        lg[e] = r;
    }

    // epilogue: each 16-lane quarter handles its own token
    const int token = token0 + (lane >> 4);
    const int sub   = lane & 15;

    float m = lg[0]; int e = 0;
    #pragma unroll
    for (int k = 1; k < NE; ++k) { if (lg[k] > m) { m = lg[k]; e = k; } }
    float z = 0.0f;
    #pragma unroll
    for (int k = 0; k < NE; ++k) z += expf(lg[k] - m);
    float gate = 1.0f / z;                 // max prob = exp(m-m)/z
    float lz   = m + logf(z);

    if (sub == 0) {
        idx_out[token]  = e;
        gate_out[token] = gate;
        atomicAdd(&sacc[8], lz * lz);
        atomicAdd(&shist[e], 1);
    }
    if (sub < NE) {
        float b0 = (sub & 1) ? lg[1] : lg[0];
        float b1 = (sub & 1) ? lg[3] : lg[2];
        float b2 = (sub & 1) ? lg[5] : lg[4];
        float b3 = (sub & 1) ? lg[7] : lg[6];
        float c0 = (sub & 2) ? b1 : b0;
        float c1 = (sub & 2) ? b3 : b2;
        float ae = (sub & 4) ? c1 : c0;
        atomicAdd(&sacc[sub], expf(ae - m) * gate);
    }

    __syncthreads();
    if (tid < 9) partials[tid*512 + blockIdx.x] = sacc[tid];
    if (tid < 8) hist[blockIdx.x*8 + tid] = shist[tid];
}

// 257 blocks x 64 threads: blocks 0..255 do rank+output for their 64-token
// window; block 256 reduces partials+counts -> aux loss. No global scan pass.
__global__ __launch_bounds__(64) void tail_kernel(
    const int* __restrict__ idx, const float* __restrict__ gate,
    const float* __restrict__ partials, const int* __restrict__ hist,
    float* __restrict__ out) {
    const int b = blockIdx.x;
    const int l = threadIdx.x;

    if (b < 256) {
        const int token = b*64 + l;
        const int e = idx[token];
        const float g = gate[token];

        // exclusive prefix over logits-blocks [0, 2b): lane l accumulates
        // hist[j][l&7] for j in chunk (l>>3) strided by 8
        int acc = 0;
        const int jend = 2*b;
        for (int j = (l >> 3); j < jend; j += 8) acc += hist[j*8 + (l & 7)];
        acc += __shfl_xor(acc, 8);
        acc += __shfl_xor(acc, 16);
        acc += __shfl_xor(acc, 32);   // every lane: total for its expert (l&7)
        const int myprefix = __shfl(acc, e);   // lane e holds expert e's prefix

        // within-window rank via ballot (lane order == token order)
        unsigned long long mymask = 0;
        #pragma unroll
        for (int q = 0; q < NE; ++q) {
            unsigned long long mk = __ballot(e == q);
            if (e == q) mymask = mk;
        }
        const unsigned long long lt = (1ull << l) - 1ull;
        const int rank = myprefix + (int)__popcll(mymask & lt);

        out[token] = (float)e;
        out[S_TOKENS + token] = (rank < CAPACITY) ? g : 0.0f;
    } else {
        // aux loss: reduce partials[9][512] and hist totals
        float vq[9];
        #pragma unroll
        for (int q = 0; q < 9; ++q) {
            float v = 0.0f;
            for (int j = l; j < 512; j += 64) v += partials[q*512 + j];
            #pragma unroll
            for (int off = 32; off > 0; off >>= 1) v += __shfl_xor(v, off);
            vq[q] = v;   // all lanes hold the total
        }
        int acc = 0;
        for (int j = (l >> 3); j < 512; j += 8) acc += hist[j*8 + (l & 7)];
        acc += __shfl_xor(acc, 8);
        acc += __shfl_xor(acc, 16);
        acc += __shfl_xor(acc, 32);   // lane e: count for expert e

        float lb = 0.0f;
        #pragma unroll
        for (int q = 0; q < NE; ++q) {
            float cq = (float)__shfl(acc, q);
            lb += cq * vq[q];
        }
        if (l == 0) {
            const float invS = 1.0f / S_TOKENS;
            out[2*S_TOKENS] = 0.01f * (vq[8] * invS) + 0.08f * (lb * invS * invS);
        }
    }
}

extern "C" void kernel_launch(void* const* d_in, const int* in_sizes, int n_in,
                              void* d_out, int out_size, void* d_ws, size_t ws_size,
                              hipStream_t stream) {
    const float* x = (const float*)d_in[0];
    const float* W = (const float*)d_in[1];
    float* out = (float*)d_out;

    int*   ws_idx  = (int*)d_ws;
    float* ws_gate = (float*)d_ws + 16384;
    float* ws_part = (float*)d_ws + 32768;   // 9*512 floats
    int*   ws_hist = (int*)d_ws + 37376;     // 512*8 ints

    logits_kernel<<<512, 512, 0, stream>>>(x, W, ws_idx, ws_gate, ws_part, ws_hist);
    tail_kernel<<<257, 64, 0, stream>>>(ws_idx, ws_gate, ws_part, ws_hist, out);
}

// Round 6
// 210.759 us; speedup vs baseline: 1.0466x; 1.0466x over previous
//
#include <hip/hip_runtime.h>

#define S_TOKENS 16384
#define DMODEL   2048
#define NE       8
#define CAPACITY 2560

// ws layout (4-byte units):
//   [0, 16384)      int    expert idx per token
//   [16384, 32768)  float  gate per token
//   [32768, 37376)  float  partials[9][512]  (q-major: psum[0..7], zsum at q=8)
//   [37376, 39424)  int    prefix[256][8]  exclusive per-span per-expert

__global__ __launch_bounds__(512) void logits_kernel(
    const float* __restrict__ x, const float* __restrict__ W,
    int* __restrict__ idx_out, float* __restrict__ gate_out,
    float* __restrict__ partials) {
    __shared__ float4 Ws4[NE][DMODEL/4];   // 64 KB, expert-major: conflict-free b128
    __shared__ float  sacc[16];            // [0..7] psum, [8] zsum

    const int tid  = threadIdx.x;
    const int wave = tid >> 6;
    const int lane = tid & 63;

    if (tid < 16) sacc[tid] = 0.0f;
    {
        const float4* __restrict__ Wg = (const float4*)W;
        float4* Wl = (float4*)Ws4;
        #pragma unroll
        for (int i = 0; i < 8; ++i) Wl[i*512 + tid] = Wg[i*512 + tid];
    }
    __syncthreads();

    // 4 tokens per wave: block covers 32 tokens
    const int token0 = blockIdx.x * 32 + wave * 4;
    const float4* __restrict__ x0 = (const float4*)(x + (size_t)token0 * DMODEL);
    const float4* __restrict__ x1 = x0 + 512;
    const float4* __restrict__ x2 = x0 + 1024;
    const float4* __restrict__ x3 = x0 + 1536;

    float a0[NE], a1[NE], a2[NE], a3[NE];
    #pragma unroll
    for (int e = 0; e < NE; ++e) { a0[e]=0; a1[e]=0; a2[e]=0; a3[e]=0; }

    // bounded unroll: keep load live-set small, no spill
    #pragma unroll 2
    for (int i = 0; i < 8; ++i) {
        const int j4 = i*64 + lane;
        float4 xv0 = x0[j4];
        float4 xv1 = x1[j4];
        float4 xv2 = x2[j4];
        float4 xv3 = x3[j4];
        #pragma unroll
        for (int e = 0; e < NE; ++e) {
            float4 w = Ws4[e][j4];
            a0[e] += xv0.x*w.x + xv0.y*w.y + xv0.z*w.z + xv0.w*w.w;
            a1[e] += xv1.x*w.x + xv1.y*w.y + xv1.z*w.z + xv1.w*w.w;
            a2[e] += xv2.x*w.x + xv2.y*w.y + xv2.z*w.z + xv2.w*w.w;
            a3[e] += xv3.x*w.x + xv3.y*w.y + xv3.z*w.z + xv3.w*w.w;
        }
    }

    // reduction with token-halving: lanes [q*16, q*16+16) end owning token q
    const bool hiHalf = (lane & 32) != 0;
    const bool oddQ   = (lane & 16) != 0;
    float lg[NE];
    #pragma unroll
    for (int e = 0; e < NE; ++e) {
        float s0 = a0[e] + __shfl_xor(a0[e], 32);
        float s1 = a1[e] + __shfl_xor(a1[e], 32);
        float s2 = a2[e] + __shfl_xor(a2[e], 32);
        float s3 = a3[e] + __shfl_xor(a3[e], 32);
        float u = hiHalf ? s2 : s0;
        float v = hiHalf ? s3 : s1;
        u += __shfl_xor(u, 16);
        v += __shfl_xor(v, 16);
        float r = oddQ ? v : u;
        r += __shfl_xor(r, 8);
        r += __shfl_xor(r, 4);
        r += __shfl_xor(r, 2);
        r += __shfl_xor(r, 1);
        lg[e] = r;
    }

    // epilogue: each 16-lane quarter handles its own token
    const int token = token0 + (lane >> 4);
    const int sub   = lane & 15;

    float m = lg[0]; int e = 0;
    #pragma unroll
    for (int k = 1; k < NE; ++k) { if (lg[k] > m) { m = lg[k]; e = k; } }
    float z = 0.0f;
    #pragma unroll
    for (int k = 0; k < NE; ++k) z += expf(lg[k] - m);
    float gate = 1.0f / z;                 // max prob = exp(m-m)/z
    float lz   = m + logf(z);

    if (sub == 0) {
        idx_out[token]  = e;
        gate_out[token] = gate;
        atomicAdd(&sacc[8], lz * lz);
    }
    if (sub < NE) {
        float b0 = (sub & 1) ? lg[1] : lg[0];
        float b1 = (sub & 1) ? lg[3] : lg[2];
        float b2 = (sub & 1) ? lg[5] : lg[4];
        float b3 = (sub & 1) ? lg[7] : lg[6];
        float c0 = (sub & 2) ? b1 : b0;
        float c1 = (sub & 2) ? b3 : b2;
        float ae = (sub & 4) ? c1 : c0;
        atomicAdd(&sacc[sub], expf(ae - m) * gate);
    }

    __syncthreads();
    if (tid < 9) partials[tid*512 + blockIdx.x] = sacc[tid];
}

__global__ __launch_bounds__(1024) void scan_kernel(
    const int* __restrict__ idx, const float* __restrict__ partials,
    int* __restrict__ prefix, float* __restrict__ aux_out) {
    __shared__ float facc[9];
    __shared__ int   cnt[256][9];   // stride 9 breaks bank alignment
    const int t    = threadIdx.x;
    const int wv   = t >> 6;      // 16 waves
    const int lane = t & 63;

    if (t < 9) facc[t] = 0.0f;
    __syncthreads();

    // phase 0: reduce per-block partials (9 x 512) on first 8 waves
    if (t < 512) {
        #pragma unroll
        for (int q = 0; q < 9; ++q) {
            float v = partials[q*512 + t];
            #pragma unroll
            for (int off = 32; off > 0; off >>= 1) v += __shfl_xor(v, off);
            if (lane == 0) atomicAdd(&facc[q], v);
        }
    }

    // phase 1: histogram; wave wv owns spans [wv*16, wv*16+16), all loads in flight
    {
        const int s0 = wv * 16;
        int ev[16];
        #pragma unroll
        for (int k = 0; k < 16; ++k) ev[k] = idx[(s0+k)*64 + lane];
        #pragma unroll
        for (int k = 0; k < 16; ++k) {
            #pragma unroll
            for (int q = 0; q < NE; ++q) {
                unsigned long long mk = __ballot(ev[k] == q);
                if (lane == q) cnt[s0+k][q] = (int)__popcll(mk);
            }
        }
    }
    __syncthreads();

    // phase 2: Hillis-Steele inclusive scan over 256 spans (threads 0-255)
    int myc[NE];
    if (t < 256) {
        #pragma unroll
        for (int q = 0; q < NE; ++q) myc[q] = cnt[t][q];
    }
    for (int off = 1; off < 256; off <<= 1) {
        int v[NE];
        if (t < 256) {
            #pragma unroll
            for (int q = 0; q < NE; ++q) v[q] = (t >= off) ? cnt[t-off][q] : 0;
        }
        __syncthreads();
        if (t < 256) {
            #pragma unroll
            for (int q = 0; q < NE; ++q) cnt[t][q] += v[q];
        }
        __syncthreads();
    }

    // exclusive prefix out + aux loss
    if (t < 256) {
        #pragma unroll
        for (int q = 0; q < NE; ++q) prefix[t*8 + q] = cnt[t][q] - myc[q];
    }
    if (t == 0) {
        float lb = 0.0f;
        #pragma unroll
        for (int q = 0; q < NE; ++q) {
            float f = (float)cnt[255][q] * (1.0f/S_TOKENS);
            float p = facc[q] * (1.0f/S_TOKENS);
            lb += f * p;
        }
        aux_out[0] = 0.01f * (facc[8] * (1.0f/S_TOKENS)) + 0.08f * lb;
    }
}

__global__ __launch_bounds__(64) void output_kernel(
    const int* __restrict__ idx, const float* __restrict__ gate,
    const int* __restrict__ prefix, float* __restrict__ out) {
    const int b = blockIdx.x;    // 256 spans of 64 tokens
    const int l = threadIdx.x;
    const int token = b*64 + l;
    const int e = idx[token];
    const float g = gate[token];

    unsigned long long mymask = 0;
    #pragma unroll
    for (int q = 0; q < NE; ++q) {
        unsigned long long mk = __ballot(e == q);
        if (e == q) mymask = mk;
    }
    unsigned long long lt = (1ull << l) - 1ull;
    int rank = prefix[b*8 + e] + (int)__popcll(mymask & lt);

    out[token] = (float)e;
    out[S_TOKENS + token] = (rank < CAPACITY) ? g : 0.0f;
}

extern "C" void kernel_launch(void* const* d_in, const int* in_sizes, int n_in,
                              void* d_out, int out_size, void* d_ws, size_t ws_size,
                              hipStream_t stream) {
    const float* x = (const float*)d_in[0];
    const float* W = (const float*)d_in[1];
    float* out = (float*)d_out;

    int*   ws_idx    = (int*)d_ws;
    float* ws_gate   = (float*)d_ws + 16384;
    float* ws_part   = (float*)d_ws + 32768;   // 9*512 floats
    int*   ws_prefix = (int*)d_ws + 37376;     // 256*8 ints

    logits_kernel<<<512, 512, 0, stream>>>(x, W, ws_idx, ws_gate, ws_part);
    scan_kernel<<<1, 1024, 0, stream>>>(ws_idx, ws_part, ws_prefix, out + 2*S_TOKENS);
    output_kernel<<<256, 64, 0, stream>>>(ws_idx, ws_gate, ws_prefix, out);
}